// Round 1
// baseline (1347.657 us; speedup 1.0000x reference)
//
#include <hip/hip_runtime.h>
#include <math.h>

#define NR 65536
#define NS 2097152

// ---------------- workspace layout ----------------
// [0, NS*16)                : float4 rgba per sample (r,g,b,alpha)
// [NS*16, NS*16+NR*4)       : int start[NR]
// [.. + NR*4)               : int end[NR]

#define ACC64(H, X, WP) do {                                            \
    const float _x = (X);                                               \
    const float* __restrict__ _w = (WP);                                \
    _Pragma("unroll")                                                   \
    for (int k = 0; k < 64; ++k) H[k] += _x * _w[k];                    \
  } while (0)

__global__ void init_bounds(int* __restrict__ start, int* __restrict__ end) {
    int r = blockIdx.x * blockDim.x + threadIdx.x;
    if (r < NR) { start[r] = 0; end[r] = 0; }
}

__global__ void find_bounds(const int* __restrict__ ridx,
                            int* __restrict__ start, int* __restrict__ end) {
    int i = blockIdx.x * blockDim.x + threadIdx.x;
    if (i >= NS) return;
    int r = ridx[i];
    if (i == 0 || ridx[i - 1] != r) start[r] = i;
    if (i == NS - 1 || ridx[i + 1] != r) end[r] = i + 1;
}

__global__ __launch_bounds__(256) void mlp_kernel(
    const float* __restrict__ rays_o, const float* __restrict__ viewdirs,
    const float* __restrict__ t_starts, const float* __restrict__ t_ends,
    const float* __restrict__ W1, const float* __restrict__ b1,
    const float* __restrict__ W2, const float* __restrict__ b2,
    const float* __restrict__ Wd, const float* __restrict__ bd,
    const float* __restrict__ Wf, const float* __restrict__ bf,
    const float* __restrict__ Wr1, const float* __restrict__ br1,
    const float* __restrict__ Wr2, const float* __restrict__ br2,
    const int* __restrict__ ridx, float4* __restrict__ rgba)
{
    int i = blockIdx.x * blockDim.x + threadIdx.x;
    if (i >= NS) return;

    int r = ridx[i];
    float ts = t_starts[i], te = t_ends[i];
    float tm = 0.5f * (ts + te);
    float ox = rays_o[3 * r + 0], oy = rays_o[3 * r + 1], oz = rays_o[3 * r + 2];
    float dx = viewdirs[3 * r + 0], dy = viewdirs[3 * r + 1], dz = viewdirs[3 * r + 2];
    float px = ox + dx * tm, py = oy + dy * tm, pz = oz + dz * tm;

    float ha[64], hb[64];

    // ---- layer 1: h1 = relu(posenc(pts, 10) @ W1 + b1) ----
    #pragma unroll
    for (int k = 0; k < 64; ++k) ha[k] = b1[k];
    ACC64(ha, px, W1 + 0 * 64);
    ACC64(ha, py, W1 + 1 * 64);
    ACC64(ha, pz, W1 + 2 * 64);
    {
        float fx = px, fy = py, fz = pz;
        for (int l = 0; l < 10; ++l) {
            float sx, cx, sy, cy, sz, cz;
            __sincosf(fx, &sx, &cx);
            __sincosf(fy, &sy, &cy);
            __sincosf(fz, &sz, &cz);
            const float* __restrict__ w = W1 + (3 + 6 * l) * 64;
            ACC64(ha, sx, w + 0 * 64);
            ACC64(ha, sy, w + 1 * 64);
            ACC64(ha, sz, w + 2 * 64);
            ACC64(ha, cx, w + 3 * 64);
            ACC64(ha, cy, w + 4 * 64);
            ACC64(ha, cz, w + 5 * 64);
            fx *= 2.0f; fy *= 2.0f; fz *= 2.0f;
        }
    }
    #pragma unroll
    for (int k = 0; k < 64; ++k) ha[k] = fmaxf(ha[k], 0.0f);

    // ---- layer 2: h2 = relu(h1 @ W2 + b2) ----
    #pragma unroll
    for (int k = 0; k < 64; ++k) hb[k] = b2[k];
    #pragma unroll
    for (int j = 0; j < 64; ++j) ACC64(hb, ha[j], W2 + j * 64);
    #pragma unroll
    for (int k = 0; k < 64; ++k) hb[k] = fmaxf(hb[k], 0.0f);

    // ---- sigma = relu(h2 @ Wd + bd) ----
    float sig = bd[0];
    #pragma unroll
    for (int j = 0; j < 64; ++j) sig += hb[j] * Wd[j];
    sig = fmaxf(sig, 0.0f);

    // ---- feat = h2 @ Wf + bf (no relu) -> ha ----
    #pragma unroll
    for (int k = 0; k < 64; ++k) ha[k] = bf[k];
    #pragma unroll
    for (int j = 0; j < 64; ++j) ACC64(ha, hb[j], Wf + j * 64);

    // ---- hd = relu([feat, posenc(d,4)] @ Wr1 + br1) -> hb ----
    #pragma unroll
    for (int k = 0; k < 64; ++k) hb[k] = br1[k];
    #pragma unroll
    for (int j = 0; j < 64; ++j) ACC64(hb, ha[j], Wr1 + j * 64);
    ACC64(hb, dx, Wr1 + 64 * 64);
    ACC64(hb, dy, Wr1 + 65 * 64);
    ACC64(hb, dz, Wr1 + 66 * 64);
    {
        float gx = dx, gy = dy, gz = dz;
        for (int l = 0; l < 4; ++l) {
            float sx, cx, sy, cy, sz, cz;
            __sincosf(gx, &sx, &cx);
            __sincosf(gy, &sy, &cy);
            __sincosf(gz, &sz, &cz);
            const float* __restrict__ w = Wr1 + (67 + 6 * l) * 64;
            ACC64(hb, sx, w + 0 * 64);
            ACC64(hb, sy, w + 1 * 64);
            ACC64(hb, sz, w + 2 * 64);
            ACC64(hb, cx, w + 3 * 64);
            ACC64(hb, cy, w + 4 * 64);
            ACC64(hb, cz, w + 5 * 64);
            gx *= 2.0f; gy *= 2.0f; gz *= 2.0f;
        }
    }
    #pragma unroll
    for (int k = 0; k < 64; ++k) hb[k] = fmaxf(hb[k], 0.0f);

    // ---- rgb = sigmoid(hd @ Wr2 + br2) ----
    float r0 = br2[0], r1 = br2[1], r2 = br2[2];
    #pragma unroll
    for (int j = 0; j < 64; ++j) {
        float h = hb[j];
        r0 += h * Wr2[j * 3 + 0];
        r1 += h * Wr2[j * 3 + 1];
        r2 += h * Wr2[j * 3 + 2];
    }
    r0 = 1.0f / (1.0f + __expf(-r0));
    r1 = 1.0f / (1.0f + __expf(-r1));
    r2 = 1.0f / (1.0f + __expf(-r2));

    float alpha = 1.0f - __expf(-sig * (te - ts));

    rgba[i] = make_float4(r0, r1, r2, alpha);
}

__global__ void render_kernel(const float4* __restrict__ rgba,
                              const float* __restrict__ t_starts,
                              const float* __restrict__ t_ends,
                              const int* __restrict__ start,
                              const int* __restrict__ end,
                              float* __restrict__ out)
{
    int r = blockIdx.x * blockDim.x + threadIdx.x;
    if (r >= NR) return;
    int s = start[r], e = end[r];
    float T = 1.0f, c0 = 0.0f, c1 = 0.0f, c2 = 0.0f, op = 0.0f, dp = 0.0f;
    for (int i = s; i < e; ++i) {
        float4 v = rgba[i];
        float w = T * v.w;
        float tmid = 0.5f * (t_starts[i] + t_ends[i]);
        c0 += w * v.x; c1 += w * v.y; c2 += w * v.z;
        op += w; dp += w * tmid;
        T *= (1.0f - v.w);
    }
    // white background
    float bg = 1.0f - op;
    c0 += bg; c1 += bg; c2 += bg;
    out[3 * r + 0] = c0;
    out[3 * r + 1] = c1;
    out[3 * r + 2] = c2;
    out[3 * NR + r] = op;
    out[4 * NR + r] = dp;
}

extern "C" void kernel_launch(void* const* d_in, const int* in_sizes, int n_in,
                              void* d_out, int out_size, void* d_ws, size_t ws_size,
                              hipStream_t stream) {
    const float* rays_o   = (const float*)d_in[0];
    const float* viewdirs = (const float*)d_in[1];
    const float* t_starts = (const float*)d_in[2];
    const float* t_ends   = (const float*)d_in[3];
    const float* W1  = (const float*)d_in[4];
    const float* b1  = (const float*)d_in[5];
    const float* W2  = (const float*)d_in[6];
    const float* b2  = (const float*)d_in[7];
    const float* Wd  = (const float*)d_in[8];
    const float* bd  = (const float*)d_in[9];
    const float* Wf  = (const float*)d_in[10];
    const float* bf  = (const float*)d_in[11];
    const float* Wr1 = (const float*)d_in[12];
    const float* br1 = (const float*)d_in[13];
    const float* Wr2 = (const float*)d_in[14];
    const float* br2 = (const float*)d_in[15];
    const int* ridx  = (const int*)d_in[16];
    float* out = (float*)d_out;

    char* ws = (char*)d_ws;
    float4* rgba = (float4*)ws;
    int* start = (int*)(ws + (size_t)NS * 16);
    int* end   = start + NR;

    init_bounds<<<NR / 256, 256, 0, stream>>>(start, end);
    find_bounds<<<NS / 256, 256, 0, stream>>>(ridx, start, end);
    mlp_kernel<<<NS / 256, 256, 0, stream>>>(
        rays_o, viewdirs, t_starts, t_ends,
        W1, b1, W2, b2, Wd, bd, Wf, bf, Wr1, br1, Wr2, br2,
        ridx, rgba);
    render_kernel<<<NR / 256, 256, 0, stream>>>(rgba, t_starts, t_ends, start, end, out);
}

// Round 2
// 217.015 us; speedup vs baseline: 6.2100x; 6.2100x over previous
//
#include <hip/hip_runtime.h>
#include <math.h>

#define NR 65536
#define NS 2097152

typedef __attribute__((ext_vector_type(4))) float f32x4;
typedef __attribute__((ext_vector_type(8))) short short8;

// ---------------- workspace layout ----------------
// [0, NS*8)                    : ushort4 rgba (bf16 r,g,b,alpha) per sample
// [NS*8, +NR*4)                : int start[NR]
// [+NR*4, +NR*4)               : int end[NR]
// [NS*8+NR*8, +36*1024)        : uint4 wfrag[36*64]  (B-fragments, bf16)

__device__ __forceinline__ ushort f2bf(float f) {
    uint u = __builtin_bit_cast(uint, f);
    u = u + 0x7fffu + ((u >> 16) & 1u);        // RNE
    return (ushort)(u >> 16);
}
__device__ __forceinline__ float bflo(uint u) { return __builtin_bit_cast(float, u << 16); }
__device__ __forceinline__ float bfhi(uint u) { return __builtin_bit_cast(float, u & 0xffff0000u); }
__device__ __forceinline__ uint packbf(float a, float b) {
    return (uint)f2bf(a) | ((uint)f2bf(b) << 16);
}

__global__ void init_bounds(int* __restrict__ start, int* __restrict__ end) {
    int r = blockIdx.x * blockDim.x + threadIdx.x;
    if (r < NR) { start[r] = 0; end[r] = 0; }
}

__global__ void find_bounds(const int* __restrict__ ridx,
                            int* __restrict__ start, int* __restrict__ end) {
    int i = blockIdx.x * blockDim.x + threadIdx.x;
    if (i >= NS) return;
    int r = ridx[i];
    if (i == 0 || ridx[i - 1] != r) start[r] = i;
    if (i == NS - 1 || ridx[i + 1] != r) end[r] = i + 1;
}

// Convert all MLP weights (f32, [K][N] row-major) into MFMA B-fragments (bf16).
// Fragment order: L1 frags 0-7, L2 8-15, Wf 16-23, Wr1 24-35.
// frag index within layer = kstep*4 + ntile; lane l holds 8 bf16:
//   B[kstep*32 + (l>>4)*8 + e][ntile*16 + (l&15)], e = 0..7.
__global__ void build_frags(const float* __restrict__ W1, const float* __restrict__ W2,
                            const float* __restrict__ Wf, const float* __restrict__ Wr1,
                            uint4* __restrict__ wfrag) {
    int t = blockIdx.x * blockDim.x + threadIdx.x;
    if (t >= 36 * 64) return;
    int f = t >> 6, lane = t & 63;
    const float* W; int kmax, fl;
    if (f < 8)       { W = W1;  kmax = 63; fl = f; }
    else if (f < 16) { W = W2;  kmax = 64; fl = f - 8; }
    else if (f < 24) { W = Wf;  kmax = 64; fl = f - 16; }
    else             { W = Wr1; kmax = 91; fl = f - 24; }
    int kstep = fl >> 2, ntile = fl & 3;
    int n  = ntile * 16 + (lane & 15);
    int kb = kstep * 32 + ((lane >> 4) * 8);
    uint q[4];
    #pragma unroll
    for (int j = 0; j < 4; ++j) {
        int k0 = kb + 2 * j, k1 = k0 + 1;
        float v0 = (k0 < kmax) ? W[k0 * 64 + n] : 0.0f;
        float v1 = (k1 < kmax) ? W[k1 * 64 + n] : 0.0f;
        q[j] = packbf(v0, v1);
    }
    wfrag[(size_t)f * 64 + lane] = make_uint4(q[0], q[1], q[2], q[3]);
}

// One MFMA layer, in-place on the wave's 64-row LDS slice.
// KS = number of 32-wide k-steps (2 or 3; kstep 2 reads from Dbuf).
template <int KS, bool RELU>
__device__ __forceinline__ void mlayer(const uint4* __restrict__ wfrag, int fb,
                                       const float* __restrict__ bias,
                                       uint4* Ab, const uint4* Db,
                                       int wavebase, int lane) {
    uint4 bfr[KS * 4];
    #pragma unroll
    for (int i = 0; i < KS * 4; ++i) bfr[i] = wfrag[(size_t)(fb + i) * 64 + lane];
    float bv[4];
    #pragma unroll
    for (int nt = 0; nt < 4; ++nt) bv[nt] = bias[nt * 16 + (lane & 15)];
    ushort* ab = (ushort*)Ab;
    #pragma unroll
    for (int mt = 0; mt < 4; ++mt) {
        int arow = wavebase + mt * 16 + (lane & 15);
        uint4 a[KS];
        a[0] = Ab[arow * 8 + (((lane >> 4) + 0) ^ (arow & 7))];
        a[1] = Ab[arow * 8 + (((lane >> 4) + 4) ^ (arow & 7))];
        if constexpr (KS == 3) a[2] = Db[arow * 4 + ((lane >> 4) ^ (arow & 3))];
        f32x4 acc[4];
        #pragma unroll
        for (int nt = 0; nt < 4; ++nt) acc[nt] = (f32x4){bv[nt], bv[nt], bv[nt], bv[nt]};
        #pragma unroll
        for (int s = 0; s < KS; ++s) {
            short8 av = __builtin_bit_cast(short8, a[s]);
            #pragma unroll
            for (int nt = 0; nt < 4; ++nt) {
                short8 bw = __builtin_bit_cast(short8, bfr[s * 4 + nt]);
                acc[nt] = __builtin_amdgcn_mfma_f32_16x16x32_bf16(av, bw, acc[nt], 0, 0, 0);
            }
        }
        // C write-back (m89 layout: col = lane&15, row = (lane>>4)*4 + reg)
        #pragma unroll
        for (int nt = 0; nt < 4; ++nt) {
            #pragma unroll
            for (int reg = 0; reg < 4; ++reg) {
                float v = acc[nt][reg];
                if (RELU) v = fmaxf(v, 0.0f);
                int wrow = wavebase + mt * 16 + (lane >> 4) * 4 + reg;
                int col  = nt * 16 + (lane & 15);
                ab[wrow * 64 + (((col >> 3) ^ (wrow & 7)) * 8) + (col & 7)] = f2bf(v);
            }
        }
    }
}

__global__ __launch_bounds__(256, 3) void fused_mlp(
    const float* __restrict__ rays_o, const float* __restrict__ viewdirs,
    const float* __restrict__ t_starts, const float* __restrict__ t_ends,
    const float* __restrict__ b1, const float* __restrict__ b2,
    const float* __restrict__ Wd, const float* __restrict__ bd,
    const float* __restrict__ bf_, const float* __restrict__ br1,
    const float* __restrict__ Wr2, const float* __restrict__ br2,
    const int* __restrict__ ridx, const uint4* __restrict__ wfrag,
    ushort4* __restrict__ rgba)
{
    __shared__ uint4 Abuf[256 * 8];   // [row][chunk^(row&7)] bf16 x8 per chunk, 32 KB
    __shared__ uint4 Dbuf[256 * 4];   // dir-enc, 16 KB

    const int tid = threadIdx.x, lane = tid & 63, wavebase = (tid >> 6) * 64;
    const int si = blockIdx.x * 256 + tid;

    int rr = ridx[si];
    float ts = t_starts[si], te = t_ends[si];
    float tm = 0.5f * (ts + te), dtv = te - ts;
    float dx = viewdirs[3 * rr + 0], dy = viewdirs[3 * rr + 1], dz = viewdirs[3 * rr + 2];
    float px = rays_o[3 * rr + 0] + dx * tm;
    float py = rays_o[3 * rr + 1] + dy * tm;
    float pz = rays_o[3 * rr + 2] + dz * tm;

    // ---- posenc(pts, 10) -> Abuf row tid ----
    {
        float enc[64];
        enc[0] = px; enc[1] = py; enc[2] = pz;
        float fx = px, fy = py, fz = pz;
        #pragma unroll
        for (int l = 0; l < 10; ++l) {
            float sx, cx, sy, cy, sz, cz;
            __sincosf(fx, &sx, &cx); __sincosf(fy, &sy, &cy); __sincosf(fz, &sz, &cz);
            enc[3 + 6 * l + 0] = sx; enc[3 + 6 * l + 1] = sy; enc[3 + 6 * l + 2] = sz;
            enc[3 + 6 * l + 3] = cx; enc[3 + 6 * l + 4] = cy; enc[3 + 6 * l + 5] = cz;
            fx *= 2.0f; fy *= 2.0f; fz *= 2.0f;
        }
        enc[63] = 0.0f;
        #pragma unroll
        for (int c = 0; c < 8; ++c) {
            uint4 q;
            q.x = packbf(enc[8 * c + 0], enc[8 * c + 1]);
            q.y = packbf(enc[8 * c + 2], enc[8 * c + 3]);
            q.z = packbf(enc[8 * c + 4], enc[8 * c + 5]);
            q.w = packbf(enc[8 * c + 6], enc[8 * c + 7]);
            Abuf[tid * 8 + (c ^ (tid & 7))] = q;
        }
    }
    // ---- posenc(d, 4) -> Dbuf row tid ----
    {
        float de[32];
        de[0] = dx; de[1] = dy; de[2] = dz;
        float gx = dx, gy = dy, gz = dz;
        #pragma unroll
        for (int l = 0; l < 4; ++l) {
            float sx, cx, sy, cy, sz, cz;
            __sincosf(gx, &sx, &cx); __sincosf(gy, &sy, &cy); __sincosf(gz, &sz, &cz);
            de[3 + 6 * l + 0] = sx; de[3 + 6 * l + 1] = sy; de[3 + 6 * l + 2] = sz;
            de[3 + 6 * l + 3] = cx; de[3 + 6 * l + 4] = cy; de[3 + 6 * l + 5] = cz;
            gx *= 2.0f; gy *= 2.0f; gz *= 2.0f;
        }
        #pragma unroll
        for (int k = 27; k < 32; ++k) de[k] = 0.0f;
        #pragma unroll
        for (int c = 0; c < 4; ++c) {
            uint4 q;
            q.x = packbf(de[8 * c + 0], de[8 * c + 1]);
            q.y = packbf(de[8 * c + 2], de[8 * c + 3]);
            q.z = packbf(de[8 * c + 4], de[8 * c + 5]);
            q.w = packbf(de[8 * c + 6], de[8 * c + 7]);
            Dbuf[tid * 4 + (c ^ (tid & 3))] = q;
        }
    }

    // waves only touch their own 64-row slice -> no __syncthreads anywhere
    mlayer<2, true >(wfrag,  0, b1,  Abuf, Dbuf, wavebase, lane);   // h1
    mlayer<2, true >(wfrag,  8, b2,  Abuf, Dbuf, wavebase, lane);   // h2

    // ---- sigma & alpha, per-thread from own h2 row ----
    float alpha;
    {
        float sig = bd[0];
        #pragma unroll
        for (int c = 0; c < 8; ++c) {
            uint4 q = Abuf[tid * 8 + (c ^ (tid & 7))];
            const uint qq[4] = {q.x, q.y, q.z, q.w};
            #pragma unroll
            for (int w = 0; w < 4; ++w) {
                int j = c * 8 + 2 * w;
                sig += bflo(qq[w]) * Wd[j] + bfhi(qq[w]) * Wd[j + 1];
            }
        }
        sig = fmaxf(sig, 0.0f);
        alpha = 1.0f - __expf(-sig * dtv);
    }

    mlayer<2, false>(wfrag, 16, bf_, Abuf, Dbuf, wavebase, lane);   // feat (no relu)
    mlayer<3, true >(wfrag, 24, br1, Abuf, Dbuf, wavebase, lane);   // hd

    // ---- rgb, per-thread from own hd row ----
    float r0 = br2[0], r1 = br2[1], r2 = br2[2];
    #pragma unroll
    for (int c = 0; c < 8; ++c) {
        uint4 q = Abuf[tid * 8 + (c ^ (tid & 7))];
        const uint qq[4] = {q.x, q.y, q.z, q.w};
        #pragma unroll
        for (int w = 0; w < 4; ++w) {
            int j = c * 8 + 2 * w;
            float lo = bflo(qq[w]), hi = bfhi(qq[w]);
            r0 += lo * Wr2[j * 3 + 0] + hi * Wr2[(j + 1) * 3 + 0];
            r1 += lo * Wr2[j * 3 + 1] + hi * Wr2[(j + 1) * 3 + 1];
            r2 += lo * Wr2[j * 3 + 2] + hi * Wr2[(j + 1) * 3 + 2];
        }
    }
    r0 = 1.0f / (1.0f + __expf(-r0));
    r1 = 1.0f / (1.0f + __expf(-r1));
    r2 = 1.0f / (1.0f + __expf(-r2));

    ushort4 o;
    o.x = f2bf(r0); o.y = f2bf(r1); o.z = f2bf(r2); o.w = f2bf(alpha);
    rgba[si] = o;
}

__global__ void render_kernel(const ushort4* __restrict__ rgba,
                              const float* __restrict__ t_starts,
                              const float* __restrict__ t_ends,
                              const int* __restrict__ start,
                              const int* __restrict__ end,
                              float* __restrict__ out)
{
    int r = blockIdx.x * blockDim.x + threadIdx.x;
    if (r >= NR) return;
    int s = start[r], e = end[r];
    float T = 1.0f, c0 = 0.0f, c1 = 0.0f, c2 = 0.0f, op = 0.0f, dp = 0.0f;
    for (int i = s; i < e; ++i) {
        ushort4 q = rgba[i];
        float vr = bflo((uint)q.x), vg = bflo((uint)q.y), vb = bflo((uint)q.z);
        float va = bflo((uint)q.w);
        float w = T * va;
        float tmid = 0.5f * (t_starts[i] + t_ends[i]);
        c0 += w * vr; c1 += w * vg; c2 += w * vb;
        op += w; dp += w * tmid;
        T *= (1.0f - va);
    }
    float bg = 1.0f - op;
    c0 += bg; c1 += bg; c2 += bg;
    out[3 * r + 0] = c0;
    out[3 * r + 1] = c1;
    out[3 * r + 2] = c2;
    out[3 * NR + r] = op;
    out[4 * NR + r] = dp;
}

extern "C" void kernel_launch(void* const* d_in, const int* in_sizes, int n_in,
                              void* d_out, int out_size, void* d_ws, size_t ws_size,
                              hipStream_t stream) {
    const float* rays_o   = (const float*)d_in[0];
    const float* viewdirs = (const float*)d_in[1];
    const float* t_starts = (const float*)d_in[2];
    const float* t_ends   = (const float*)d_in[3];
    const float* W1  = (const float*)d_in[4];
    const float* b1  = (const float*)d_in[5];
    const float* W2  = (const float*)d_in[6];
    const float* b2  = (const float*)d_in[7];
    const float* Wd  = (const float*)d_in[8];
    const float* bd  = (const float*)d_in[9];
    const float* Wf  = (const float*)d_in[10];
    const float* bf_ = (const float*)d_in[11];
    const float* Wr1 = (const float*)d_in[12];
    const float* br1 = (const float*)d_in[13];
    const float* Wr2 = (const float*)d_in[14];
    const float* br2 = (const float*)d_in[15];
    const int* ridx  = (const int*)d_in[16];
    float* out = (float*)d_out;

    char* ws = (char*)d_ws;
    ushort4* rgba = (ushort4*)ws;
    int* start = (int*)(ws + (size_t)NS * 8);
    int* end   = start + NR;
    uint4* wfrag = (uint4*)(ws + (size_t)NS * 8 + (size_t)NR * 8);

    build_frags<<<9, 256, 0, stream>>>(W1, W2, Wf, Wr1, wfrag);
    init_bounds<<<NR / 256, 256, 0, stream>>>(start, end);
    find_bounds<<<NS / 256, 256, 0, stream>>>(ridx, start, end);
    fused_mlp<<<NS / 256, 256, 0, stream>>>(
        rays_o, viewdirs, t_starts, t_ends,
        b1, b2, Wd, bd, bf_, br1, Wr2, br2,
        ridx, wfrag, rgba);
    render_kernel<<<NR / 256, 256, 0, stream>>>(rgba, t_starts, t_ends, start, end, out);
}

// Round 4
// 194.230 us; speedup vs baseline: 6.9385x; 1.1173x over previous
//
#include <hip/hip_runtime.h>
#include <math.h>

#define NR 65536
#define NS 2097152

typedef __attribute__((ext_vector_type(4))) float f32x4;
typedef __attribute__((ext_vector_type(8))) short short8;

#define RSTRIDE 17          // dwords per 16-sample row (16 + 1 pad)
#define GSTRIDE (48 * 17)   // dwords per 16-sample group (816; 816 % 32 == 16)

// ---------------- workspace layout ----------------
// [0, NS*8)                : uint2 rgba (bf16 r,g | b,alpha) per sample
// [NS*8, +NR*4)            : int start[NR]
// [+NR*4, +NR*4)           : int end[NR]
// [NS*8+NR*8, +40KB)       : uint4 wfrag[40*64]  (A-fragments, bf16, W^T)

__device__ __forceinline__ ushort f2bf(float f) {
    uint u = __builtin_bit_cast(uint, f);
    u = u + 0x7fffu + ((u >> 16) & 1u);        // RNE
    return (ushort)(u >> 16);
}
__device__ __forceinline__ uint packbf(float a, float b) {
    return (uint)f2bf(a) | ((uint)f2bf(b) << 16);
}
__device__ __forceinline__ float bflo(uint u) { return __builtin_bit_cast(float, u << 16); }

__global__ void init_bounds(int* __restrict__ start, int* __restrict__ end) {
    int r = blockIdx.x * blockDim.x + threadIdx.x;
    if (r < NR) { start[r] = 0; end[r] = 0; }
}

__global__ void find_bounds(const int* __restrict__ ridx,
                            int* __restrict__ start, int* __restrict__ end) {
    int i = blockIdx.x * blockDim.x + threadIdx.x;
    if (i >= NS) return;
    int r = ridx[i];
    if (i == 0 || ridx[i - 1] != r) start[r] = i;
    if (i == NS - 1 || ridx[i + 1] != r) end[r] = i + 1;
}

// A-fragments = W^T: lane holds A[m = 16ft + (l&15)][k = 32ks + (l>>4)*8 + e]
//             = W[k][16ft + (l&15)]  (identical gather to the round-2-proven frags).
// Order: L1 0-7 (f = ks*4+ft), L2 8-15, Wf 16-23, Wr1 24-35, Wd 36-37, Wr2 38-39.
__global__ void build_frags(const float* __restrict__ W1, const float* __restrict__ W2,
                            const float* __restrict__ Wf, const float* __restrict__ Wr1,
                            const float* __restrict__ Wd, const float* __restrict__ Wr2,
                            uint4* __restrict__ wfrag) {
    int t = blockIdx.x * blockDim.x + threadIdx.x;
    if (t >= 40 * 64) return;
    int f = t >> 6, lane = t & 63;
    int c = lane & 15;
    uint q[4];
    if (f < 36) {
        const float* W; int kmax, fl;
        if (f < 8)       { W = W1;  kmax = 63; fl = f; }
        else if (f < 16) { W = W2;  kmax = 64; fl = f - 8; }
        else if (f < 24) { W = Wf;  kmax = 64; fl = f - 16; }
        else             { W = Wr1; kmax = 91; fl = f - 24; }
        int ks = fl >> 2, ft = fl & 3;
        int n = ft * 16 + c;
        int kb = ks * 32 + ((lane >> 4) * 8);
        #pragma unroll
        for (int j = 0; j < 4; ++j) {
            int k0 = kb + 2 * j, k1 = k0 + 1;
            float v0 = (k0 < kmax) ? W[k0 * 64 + n] : 0.0f;
            float v1 = (k1 < kmax) ? W[k1 * 64 + n] : 0.0f;
            q[j] = packbf(v0, v1);
        }
    } else if (f < 38) {          // sigma tile: A[m][k] = (m==0) ? Wd[k] : 0
        int kb = (f - 36) * 32 + ((lane >> 4) * 8);
        #pragma unroll
        for (int j = 0; j < 4; ++j) {
            float v0 = (c == 0) ? Wd[kb + 2 * j] : 0.0f;
            float v1 = (c == 0) ? Wd[kb + 2 * j + 1] : 0.0f;
            q[j] = packbf(v0, v1);
        }
    } else {                      // rgb tile: A[m][k] = (m<3) ? Wr2[k*3+m] : 0
        int kb = (f - 38) * 32 + ((lane >> 4) * 8);
        #pragma unroll
        for (int j = 0; j < 4; ++j) {
            float v0 = (c < 3) ? Wr2[(kb + 2 * j) * 3 + c] : 0.0f;
            float v1 = (c < 3) ? Wr2[(kb + 2 * j + 1) * 3 + c] : 0.0f;
            q[j] = packbf(v0, v1);
        }
    }
    wfrag[(size_t)f * 64 + lane] = make_uint4(q[0], q[1], q[2], q[3]);
}

// LDS activation layout, per (wave, sample-tile st) group of 16 samples:
//   group base (dwords) = (wave*4 + st) * GSTRIDE
//   row kp (k-pair) at offset kp*RSTRIDE; dword (kp, s) = bf16{k=2kp, 2kp+1} of sample s
// Rows 0-31: activations (64 feats, updated in place per layer). Rows 32-47: dir-enc.

template <int KS, bool RELU, bool SIGMA>
__device__ __forceinline__ void dense_layer(uint* S, const uint4* __restrict__ wfrag,
                                            int fb, const float* __restrict__ bias,
                                            float bd0, uint wb, int lane,
                                            float* sigout) {
    const int g = lane >> 4, s = lane & 15;
    uint4 wf[KS * 4];
    #pragma unroll
    for (int i = 0; i < KS * 4; ++i) wf[i] = wfrag[(size_t)(fb + i) * 64 + lane];
    uint4 wsg[2];
    if constexpr (SIGMA) {
        wsg[0] = wfrag[36 * 64 + lane];
        wsg[1] = wfrag[37 * 64 + lane];
    }
    float4 bfr[4];
    #pragma unroll
    for (int ft = 0; ft < 4; ++ft)
        bfr[ft] = *(const float4*)(bias + 16 * ft + 4 * g);

    #pragma unroll
    for (int st = 0; st < 4; ++st) {
        uint stb = wb + (uint)st * (uint)GSTRIDE;
        uint4 B[KS];
        #pragma unroll
        for (int ks = 0; ks < KS; ++ks) {
            uint A00 = stb + (uint)((16 * ks + 4 * g) * RSTRIDE) + (uint)s;
            B[ks].x = S[A00];
            B[ks].y = S[A00 + RSTRIDE];
            B[ks].z = S[A00 + 2 * RSTRIDE];
            B[ks].w = S[A00 + 3 * RSTRIDE];
        }
        f32x4 acc[4];
        #pragma unroll
        for (int ft = 0; ft < 4; ++ft)
            acc[ft] = (f32x4){bfr[ft].x, bfr[ft].y, bfr[ft].z, bfr[ft].w};
        f32x4 sacc;
        if constexpr (SIGMA) sacc = (f32x4){(g == 0) ? bd0 : 0.0f, 0.0f, 0.0f, 0.0f};
        #pragma unroll
        for (int ks = 0; ks < KS; ++ks) {
            short8 bv = __builtin_bit_cast(short8, B[ks]);
            #pragma unroll
            for (int ft = 0; ft < 4; ++ft)
                acc[ft] = __builtin_amdgcn_mfma_f32_16x16x32_bf16(
                    __builtin_bit_cast(short8, wf[ks * 4 + ft]), bv, acc[ft], 0, 0, 0);
            if constexpr (SIGMA)
                sacc = __builtin_amdgcn_mfma_f32_16x16x32_bf16(
                    __builtin_bit_cast(short8, wsg[ks]), bv, sacc, 0, 0, 0);
        }
        // D layout: col = lane&15 = sample, row = 4g + reg = out-feature
        #pragma unroll
        for (int ft = 0; ft < 4; ++ft) {
            float a0 = acc[ft][0], a1 = acc[ft][1], a2 = acc[ft][2], a3 = acc[ft][3];
            if constexpr (RELU) {
                a0 = fmaxf(a0, 0.0f); a1 = fmaxf(a1, 0.0f);
                a2 = fmaxf(a2, 0.0f); a3 = fmaxf(a3, 0.0f);
            }
            uint W00 = stb + (uint)((8 * ft + 2 * g) * RSTRIDE) + (uint)s;
            S[W00]           = packbf(a0, a1);
            S[W00 + RSTRIDE] = packbf(a2, a3);
        }
        if constexpr (SIGMA) sigout[st] = sacc[0];
    }
}

__global__ __launch_bounds__(256, 3) void fused_mlp(
    const float* __restrict__ rays_o, const float* __restrict__ viewdirs,
    const float* __restrict__ t_starts, const float* __restrict__ t_ends,
    const float* __restrict__ b1, const float* __restrict__ b2,
    const float* __restrict__ bd, const float* __restrict__ bf_,
    const float* __restrict__ br1, const float* __restrict__ br2,
    const int* __restrict__ ridx, const uint4* __restrict__ wfrag,
    uint2* __restrict__ rgba)
{
    __shared__ uint S[16 * GSTRIDE];   // 13056 dwords = 51 KB
    __shared__ float dtl[256];

    const int tid = threadIdx.x;
    const int w = tid >> 6, lane = tid & 63;
    const int g = lane >> 4, s = lane & 15;
    const uint wb = (uint)(w * 4) * (uint)GSTRIDE;
    const int si = blockIdx.x * 256 + tid;

    int rr = ridx[si];
    float ts = t_starts[si], te = t_ends[si];
    float tm = 0.5f * (ts + te), dtv = te - ts;
    float dx = viewdirs[3 * rr + 0], dy = viewdirs[3 * rr + 1], dz = viewdirs[3 * rr + 2];
    float px = rays_o[3 * rr + 0] + dx * tm;
    float py = rays_o[3 * rr + 1] + dy * tm;
    float pz = rays_o[3 * rr + 2] + dz * tm;
    dtl[tid] = dtv;

    const uint pb = wb + (uint)g * (uint)GSTRIDE + (uint)s;

    // ---- posenc(pts,10): feats 0..62 (+0 pad) -> rows 0..31 ----
    {
        float enc[64];
        enc[0] = px; enc[1] = py; enc[2] = pz;
        float fx = px, fy = py, fz = pz;
        #pragma unroll
        for (int l = 0; l < 10; ++l) {
            float sx, cx, sy, cy, sz, cz;
            __sincosf(fx, &sx, &cx); __sincosf(fy, &sy, &cy); __sincosf(fz, &sz, &cz);
            enc[3 + 6 * l + 0] = sx; enc[3 + 6 * l + 1] = sy; enc[3 + 6 * l + 2] = sz;
            enc[3 + 6 * l + 3] = cx; enc[3 + 6 * l + 4] = cy; enc[3 + 6 * l + 5] = cz;
            fx *= 2.0f; fy *= 2.0f; fz *= 2.0f;
        }
        enc[63] = 0.0f;
        #pragma unroll
        for (int kp = 0; kp < 32; ++kp)
            S[pb + (uint)(kp * RSTRIDE)] = packbf(enc[2 * kp], enc[2 * kp + 1]);
    }
    // ---- posenc(d,4): feats 0..26 (+pad) -> rows 32..47 ----
    {
        float de[32];
        de[0] = dx; de[1] = dy; de[2] = dz;
        float gx = dx, gy = dy, gz = dz;
        #pragma unroll
        for (int l = 0; l < 4; ++l) {
            float sx, cx, sy, cy, sz, cz;
            __sincosf(gx, &sx, &cx); __sincosf(gy, &sy, &cy); __sincosf(gz, &sz, &cz);
            de[3 + 6 * l + 0] = sx; de[3 + 6 * l + 1] = sy; de[3 + 6 * l + 2] = sz;
            de[3 + 6 * l + 3] = cx; de[3 + 6 * l + 4] = cy; de[3 + 6 * l + 5] = cz;
            gx *= 2.0f; gy *= 2.0f; gz *= 2.0f;
        }
        #pragma unroll
        for (int k = 27; k < 32; ++k) de[k] = 0.0f;
        #pragma unroll
        for (int kp = 32; kp < 48; ++kp)
            S[pb + (uint)(kp * RSTRIDE)] = packbf(de[2 * kp - 64], de[2 * kp - 63]);
    }

    float sig4[4];
    float bd0 = bd[0];

    dense_layer<2, true,  false>(S, wfrag,  0, b1,  0.0f, wb, lane, sig4);  // h1
    dense_layer<2, true,  false>(S, wfrag,  8, b2,  0.0f, wb, lane, sig4);  // h2
    dense_layer<2, false, true >(S, wfrag, 16, bf_, bd0,  wb, lane, sig4);  // feat + sigma
    dense_layer<3, true,  false>(S, wfrag, 24, br1, 0.0f, wb, lane, sig4);  // hd

    // ---- rgb tile + epilogue ----
    {
        uint4 wr0 = wfrag[38 * 64 + lane], wr1f = wfrag[39 * 64 + lane];
        float c0 = br2[0], c1 = br2[1], c2 = br2[2];
        #pragma unroll
        for (int st = 0; st < 4; ++st) {
            uint stb = wb + (uint)st * (uint)GSTRIDE;
            uint4 B0, B1;
            {
                uint A00 = stb + (uint)((4 * g) * RSTRIDE) + (uint)s;
                B0.x = S[A00]; B0.y = S[A00 + RSTRIDE];
                B0.z = S[A00 + 2 * RSTRIDE]; B0.w = S[A00 + 3 * RSTRIDE];
            }
            {
                uint A00 = stb + (uint)((16 + 4 * g) * RSTRIDE) + (uint)s;
                B1.x = S[A00]; B1.y = S[A00 + RSTRIDE];
                B1.z = S[A00 + 2 * RSTRIDE]; B1.w = S[A00 + 3 * RSTRIDE];
            }
            f32x4 acc = (g == 0) ? (f32x4){c0, c1, c2, 0.0f}
                                 : (f32x4){0.0f, 0.0f, 0.0f, 0.0f};
            acc = __builtin_amdgcn_mfma_f32_16x16x32_bf16(
                __builtin_bit_cast(short8, wr0), __builtin_bit_cast(short8, B0), acc, 0, 0, 0);
            acc = __builtin_amdgcn_mfma_f32_16x16x32_bf16(
                __builtin_bit_cast(short8, wr1f), __builtin_bit_cast(short8, B1), acc, 0, 0, 0);
            if (lane < 16) {
                float sg = fmaxf(sig4[st], 0.0f);
                float dte = dtl[w * 64 + st * 16 + lane];
                float alpha = 1.0f - __expf(-sg * dte);
                float r0 = 1.0f / (1.0f + __expf(-acc[0]));
                float r1 = 1.0f / (1.0f + __expf(-acc[1]));
                float r2 = 1.0f / (1.0f + __expf(-acc[2]));
                uint2 o;
                o.x = packbf(r0, r1);
                o.y = packbf(r2, alpha);
                rgba[blockIdx.x * 256 + w * 64 + st * 16 + lane] = o;
            }
        }
    }
}

__global__ void render_kernel(const uint2* __restrict__ rgba,
                              const float* __restrict__ t_starts,
                              const float* __restrict__ t_ends,
                              const int* __restrict__ start,
                              const int* __restrict__ end,
                              float* __restrict__ out)
{
    int r = blockIdx.x * blockDim.x + threadIdx.x;
    if (r >= NR) return;
    int sb = start[r], e = end[r];
    float T = 1.0f, c0 = 0.0f, c1 = 0.0f, c2 = 0.0f, op = 0.0f, dp = 0.0f;
    for (int i = sb; i < e; ++i) {
        uint2 q = rgba[i];
        float vr = bflo(q.x & 0xffffu), vg = bflo(q.x >> 16);
        float vb = bflo(q.y & 0xffffu), va = bflo(q.y >> 16);
        float wgt = T * va;
        float tmid = 0.5f * (t_starts[i] + t_ends[i]);
        c0 += wgt * vr; c1 += wgt * vg; c2 += wgt * vb;
        op += wgt; dp += wgt * tmid;
        T *= (1.0f - va);
    }
    float bg = 1.0f - op;
    c0 += bg; c1 += bg; c2 += bg;
    out[3 * r + 0] = c0;
    out[3 * r + 1] = c1;
    out[3 * r + 2] = c2;
    out[3 * NR + r] = op;
    out[4 * NR + r] = dp;
}

extern "C" void kernel_launch(void* const* d_in, const int* in_sizes, int n_in,
                              void* d_out, int out_size, void* d_ws, size_t ws_size,
                              hipStream_t stream) {
    const float* rays_o   = (const float*)d_in[0];
    const float* viewdirs = (const float*)d_in[1];
    const float* t_starts = (const float*)d_in[2];
    const float* t_ends   = (const float*)d_in[3];
    const float* W1  = (const float*)d_in[4];
    const float* b1  = (const float*)d_in[5];
    const float* W2  = (const float*)d_in[6];
    const float* b2  = (const float*)d_in[7];
    const float* Wd  = (const float*)d_in[8];
    const float* bd  = (const float*)d_in[9];
    const float* Wf  = (const float*)d_in[10];
    const float* bf_ = (const float*)d_in[11];
    const float* Wr1 = (const float*)d_in[12];
    const float* br1 = (const float*)d_in[13];
    const float* Wr2 = (const float*)d_in[14];
    const float* br2 = (const float*)d_in[15];
    const int* ridx  = (const int*)d_in[16];
    float* out = (float*)d_out;

    char* ws = (char*)d_ws;
    uint2* rgba = (uint2*)ws;
    int* start = (int*)(ws + (size_t)NS * 8);
    int* end   = start + NR;
    uint4* wfrag = (uint4*)(ws + (size_t)NS * 8 + (size_t)NR * 8);

    build_frags<<<10, 256, 0, stream>>>(W1, W2, Wf, Wr1, Wd, Wr2, wfrag);
    init_bounds<<<NR / 256, 256, 0, stream>>>(start, end);
    find_bounds<<<NS / 256, 256, 0, stream>>>(ridx, start, end);
    fused_mlp<<<NS / 256, 256, 0, stream>>>(
        rays_o, viewdirs, t_starts, t_ends,
        b1, b2, bd, bf_, br1, br2, ridx, wfrag, rgba);
    render_kernel<<<NR / 256, 256, 0, stream>>>(rgba, t_starts, t_ends, start, end, out);
}

// Round 6
// 178.965 us; speedup vs baseline: 7.5303x; 1.0853x over previous
//
#include <hip/hip_runtime.h>
#include <math.h>

#define NR 65536
#define NS 2097152

typedef __attribute__((ext_vector_type(4))) float f32x4;
typedef __attribute__((ext_vector_type(8))) short short8;

#define RSTRIDE 17          // dwords per 16-sample row (16 + 1 pad)
#define GSTRIDE (48 * 17)   // dwords per 16-sample group (816)

// ---------------- workspace layout ----------------
// [0, NS*8)                : uint2 rgba (bf16 r,g | b,alpha) per sample
// [NS*8, +NR*4)            : int start[NR]
// [+NR*4, +NR*4)           : int end[NR]
// [NS*8+NR*8, +40KB)       : uint4 wfrag[40*64]  (A-fragments, bf16, W^T)

// Native bf16 conversion (RNE fptrunc) — compiler lowers to HW cvt / cvt_pk.
__device__ __forceinline__ uint packbf(float a, float b) {
    __bf16 lo = (__bf16)a, hi = (__bf16)b;
    ushort ul = __builtin_bit_cast(ushort, lo);
    ushort uh = __builtin_bit_cast(ushort, hi);
    return (uint)ul | ((uint)uh << 16);
}
__device__ __forceinline__ float bflo(uint u) { return __builtin_bit_cast(float, u << 16); }

__global__ void init_bounds(int* __restrict__ start, int* __restrict__ end) {
    int r = blockIdx.x * blockDim.x + threadIdx.x;
    if (r < NR) { start[r] = 0; end[r] = 0; }
}

__global__ void find_bounds(const int* __restrict__ ridx,
                            int* __restrict__ start, int* __restrict__ end) {
    int i = blockIdx.x * blockDim.x + threadIdx.x;
    if (i >= NS) return;
    int r = ridx[i];
    if (i == 0 || ridx[i - 1] != r) start[r] = i;
    if (i == NS - 1 || ridx[i + 1] != r) end[r] = i + 1;
}

// A-fragments = W^T: lane holds A[m = 16ft + (l&15)][k = 32ks + (l>>4)*8 + e]
//             = W[k][16ft + (l&15)].
// Order: L1 0-7 (f = ks*4+ft), L2 8-15, Wf 16-23, Wr1 24-35, Wd 36-37, Wr2 38-39.
__global__ void build_frags(const float* __restrict__ W1, const float* __restrict__ W2,
                            const float* __restrict__ Wf, const float* __restrict__ Wr1,
                            const float* __restrict__ Wd, const float* __restrict__ Wr2,
                            uint4* __restrict__ wfrag) {
    int t = blockIdx.x * blockDim.x + threadIdx.x;
    if (t >= 40 * 64) return;
    int f = t >> 6, lane = t & 63;
    int c = lane & 15;
    uint q[4];
    if (f < 36) {
        const float* W; int kmax, fl;
        if (f < 8)       { W = W1;  kmax = 63; fl = f; }
        else if (f < 16) { W = W2;  kmax = 64; fl = f - 8; }
        else if (f < 24) { W = Wf;  kmax = 64; fl = f - 16; }
        else             { W = Wr1; kmax = 91; fl = f - 24; }
        int ks = fl >> 2, ft = fl & 3;
        int n = ft * 16 + c;
        int kb = ks * 32 + ((lane >> 4) * 8);
        #pragma unroll
        for (int j = 0; j < 4; ++j) {
            int k0 = kb + 2 * j, k1 = k0 + 1;
            float v0 = (k0 < kmax) ? W[k0 * 64 + n] : 0.0f;
            float v1 = (k1 < kmax) ? W[k1 * 64 + n] : 0.0f;
            q[j] = packbf(v0, v1);
        }
    } else if (f < 38) {          // sigma tile: A[m][k] = (m==0) ? Wd[k] : 0
        int kb = (f - 36) * 32 + ((lane >> 4) * 8);
        #pragma unroll
        for (int j = 0; j < 4; ++j) {
            float v0 = (c == 0) ? Wd[kb + 2 * j] : 0.0f;
            float v1 = (c == 0) ? Wd[kb + 2 * j + 1] : 0.0f;
            q[j] = packbf(v0, v1);
        }
    } else {                      // rgb tile: A[m][k] = (m<3) ? Wr2[k*3+m] : 0
        int kb = (f - 38) * 32 + ((lane >> 4) * 8);
        #pragma unroll
        for (int j = 0; j < 4; ++j) {
            float v0 = (c < 3) ? Wr2[(kb + 2 * j) * 3 + c] : 0.0f;
            float v1 = (c < 3) ? Wr2[(kb + 2 * j + 1) * 3 + c] : 0.0f;
            q[j] = packbf(v0, v1);
        }
    }
    wfrag[(size_t)f * 64 + lane] = make_uint4(q[0], q[1], q[2], q[3]);
}

// LDS activation layout, per (wave, sample-tile st) group of 16 samples:
//   group base (dwords) = (wave*4 + st) * GSTRIDE
//   row kp (k-pair) at offset kp*RSTRIDE; dword (kp, s) = bf16{k=2kp, 2kp+1} of sample s
// Rows 0-31: activations (64 feats, updated in place per layer). Rows 32-47: dir-enc.

template <int KS, bool RELU, bool SIGMA>
__device__ __forceinline__ void dense_layer(uint* S, const uint4* __restrict__ wfrag,
                                            int fb, const float* __restrict__ bias,
                                            float bd0, uint wb, int lane,
                                            float* sigout) {
    const int g = lane >> 4, s = lane & 15;
    uint4 wf[KS * 4];
    #pragma unroll
    for (int i = 0; i < KS * 4; ++i) wf[i] = wfrag[(size_t)(fb + i) * 64 + lane];
    uint4 wsg[2];
    if constexpr (SIGMA) {
        wsg[0] = wfrag[36 * 64 + lane];
        wsg[1] = wfrag[37 * 64 + lane];
    }
    float4 bfr[4];
    #pragma unroll
    for (int ft = 0; ft < 4; ++ft)
        bfr[ft] = *(const float4*)(bias + 16 * ft + 4 * g);

    #pragma unroll
    for (int st = 0; st < 4; ++st) {
        uint stb = wb + (uint)st * (uint)GSTRIDE;
        uint4 B[KS];
        #pragma unroll
        for (int ks = 0; ks < KS; ++ks) {
            uint A00 = stb + (uint)((16 * ks + 4 * g) * RSTRIDE) + (uint)s;
            B[ks].x = S[A00];
            B[ks].y = S[A00 + RSTRIDE];
            B[ks].z = S[A00 + 2 * RSTRIDE];
            B[ks].w = S[A00 + 3 * RSTRIDE];
        }
        f32x4 acc[4];
        #pragma unroll
        for (int ft = 0; ft < 4; ++ft)
            acc[ft] = (f32x4){bfr[ft].x, bfr[ft].y, bfr[ft].z, bfr[ft].w};
        f32x4 sacc;
        if constexpr (SIGMA) sacc = (f32x4){(g == 0) ? bd0 : 0.0f, 0.0f, 0.0f, 0.0f};
        #pragma unroll
        for (int ks = 0; ks < KS; ++ks) {
            short8 bv = __builtin_bit_cast(short8, B[ks]);
            #pragma unroll
            for (int ft = 0; ft < 4; ++ft)
                acc[ft] = __builtin_amdgcn_mfma_f32_16x16x32_bf16(
                    __builtin_bit_cast(short8, wf[ks * 4 + ft]), bv, acc[ft], 0, 0, 0);
            if constexpr (SIGMA)
                sacc = __builtin_amdgcn_mfma_f32_16x16x32_bf16(
                    __builtin_bit_cast(short8, wsg[ks]), bv, sacc, 0, 0, 0);
        }
        // D layout: col = lane&15 = sample, row = 4g + reg = out-feature
        #pragma unroll
        for (int ft = 0; ft < 4; ++ft) {
            float a0 = acc[ft][0], a1 = acc[ft][1], a2 = acc[ft][2], a3 = acc[ft][3];
            if constexpr (RELU) {
                a0 = fmaxf(a0, 0.0f); a1 = fmaxf(a1, 0.0f);
                a2 = fmaxf(a2, 0.0f); a3 = fmaxf(a3, 0.0f);
            }
            uint W00 = stb + (uint)((8 * ft + 2 * g) * RSTRIDE) + (uint)s;
            S[W00]           = packbf(a0, a1);
            S[W00 + RSTRIDE] = packbf(a2, a3);
        }
        if constexpr (SIGMA) sigout[st] = sacc[0];
    }
}

__global__ __launch_bounds__(256, 3) void fused_mlp(
    const float* __restrict__ rays_o, const float* __restrict__ viewdirs,
    const float* __restrict__ t_starts, const float* __restrict__ t_ends,
    const float* __restrict__ b1, const float* __restrict__ b2,
    const float* __restrict__ bd, const float* __restrict__ bf_,
    const float* __restrict__ br1, const float* __restrict__ br2,
    const int* __restrict__ ridx, const uint4* __restrict__ wfrag,
    uint2* __restrict__ rgba)
{
    __shared__ uint S[16 * GSTRIDE];   // 13056 dwords = 51 KB
    __shared__ float dtl[256];

    const int tid = threadIdx.x;
    const int w = tid >> 6, lane = tid & 63;
    const int g = lane >> 4, s = lane & 15;
    const uint wb = (uint)(w * 4) * (uint)GSTRIDE;
    const int si = blockIdx.x * 256 + tid;

    int rr = ridx[si];
    float ts = t_starts[si], te = t_ends[si];
    float tm = 0.5f * (ts + te), dtv = te - ts;
    float dx = viewdirs[3 * rr + 0], dy = viewdirs[3 * rr + 1], dz = viewdirs[3 * rr + 2];
    float px = rays_o[3 * rr + 0] + dx * tm;
    float py = rays_o[3 * rr + 1] + dy * tm;
    float pz = rays_o[3 * rr + 2] + dz * tm;
    dtl[tid] = dtv;

    const uint pb = wb + (uint)g * (uint)GSTRIDE + (uint)s;

    // ---- posenc(pts,10) via double-angle recurrence -> rows 0..31 ----
    {
        float enc[64];
        enc[0] = px; enc[1] = py; enc[2] = pz;
        float sx = __sinf(px), cx = __cosf(px);
        float sy = __sinf(py), cy = __cosf(py);
        float sz = __sinf(pz), cz = __cosf(pz);
        #pragma unroll
        for (int l = 0; l < 10; ++l) {
            enc[3 + 6 * l + 0] = sx; enc[3 + 6 * l + 1] = sy; enc[3 + 6 * l + 2] = sz;
            enc[3 + 6 * l + 3] = cx; enc[3 + 6 * l + 4] = cy; enc[3 + 6 * l + 5] = cz;
            float nsx = 2.0f * sx * cx, nsy = 2.0f * sy * cy, nsz = 2.0f * sz * cz;
            cx = fmaf(-2.0f * sx, sx, 1.0f);
            cy = fmaf(-2.0f * sy, sy, 1.0f);
            cz = fmaf(-2.0f * sz, sz, 1.0f);
            sx = nsx; sy = nsy; sz = nsz;
        }
        enc[63] = 0.0f;
        #pragma unroll
        for (int kp = 0; kp < 32; ++kp)
            S[pb + (uint)(kp * RSTRIDE)] = packbf(enc[2 * kp], enc[2 * kp + 1]);
    }
    // ---- posenc(d,4) via double-angle recurrence -> rows 32..47 ----
    {
        float de[32];
        de[0] = dx; de[1] = dy; de[2] = dz;
        float sx = __sinf(dx), cx = __cosf(dx);
        float sy = __sinf(dy), cy = __cosf(dy);
        float sz = __sinf(dz), cz = __cosf(dz);
        #pragma unroll
        for (int l = 0; l < 4; ++l) {
            de[3 + 6 * l + 0] = sx; de[3 + 6 * l + 1] = sy; de[3 + 6 * l + 2] = sz;
            de[3 + 6 * l + 3] = cx; de[3 + 6 * l + 4] = cy; de[3 + 6 * l + 5] = cz;
            float nsx = 2.0f * sx * cx, nsy = 2.0f * sy * cy, nsz = 2.0f * sz * cz;
            cx = fmaf(-2.0f * sx, sx, 1.0f);
            cy = fmaf(-2.0f * sy, sy, 1.0f);
            cz = fmaf(-2.0f * sz, sz, 1.0f);
            sx = nsx; sy = nsy; sz = nsz;
        }
        #pragma unroll
        for (int k = 27; k < 32; ++k) de[k] = 0.0f;
        #pragma unroll
        for (int kp = 32; kp < 48; ++kp)
            S[pb + (uint)(kp * RSTRIDE)] = packbf(de[2 * kp - 64], de[2 * kp - 63]);
    }

    float sig4[4];
    float bd0 = bd[0];

    dense_layer<2, true,  false>(S, wfrag,  0, b1,  0.0f, wb, lane, sig4);  // h1
    dense_layer<2, true,  false>(S, wfrag,  8, b2,  0.0f, wb, lane, sig4);  // h2
    dense_layer<2, false, true >(S, wfrag, 16, bf_, bd0,  wb, lane, sig4);  // feat + sigma
    dense_layer<3, true,  false>(S, wfrag, 24, br1, 0.0f, wb, lane, sig4);  // hd

    // ---- rgb tile + epilogue ----
    {
        uint4 wr0 = wfrag[38 * 64 + lane], wr1f = wfrag[39 * 64 + lane];
        float c0 = br2[0], c1 = br2[1], c2 = br2[2];
        #pragma unroll
        for (int st = 0; st < 4; ++st) {
            uint stb = wb + (uint)st * (uint)GSTRIDE;
            uint4 B0, B1;
            {
                uint A00 = stb + (uint)((4 * g) * RSTRIDE) + (uint)s;
                B0.x = S[A00]; B0.y = S[A00 + RSTRIDE];
                B0.z = S[A00 + 2 * RSTRIDE]; B0.w = S[A00 + 3 * RSTRIDE];
            }
            {
                uint A00 = stb + (uint)((16 + 4 * g) * RSTRIDE) + (uint)s;
                B1.x = S[A00]; B1.y = S[A00 + RSTRIDE];
                B1.z = S[A00 + 2 * RSTRIDE]; B1.w = S[A00 + 3 * RSTRIDE];
            }
            f32x4 acc = (g == 0) ? (f32x4){c0, c1, c2, 0.0f}
                                 : (f32x4){0.0f, 0.0f, 0.0f, 0.0f};
            acc = __builtin_amdgcn_mfma_f32_16x16x32_bf16(
                __builtin_bit_cast(short8, wr0), __builtin_bit_cast(short8, B0), acc, 0, 0, 0);
            acc = __builtin_amdgcn_mfma_f32_16x16x32_bf16(
                __builtin_bit_cast(short8, wr1f), __builtin_bit_cast(short8, B1), acc, 0, 0, 0);
            if (lane < 16) {
                float sg = fmaxf(sig4[st], 0.0f);
                float dte = dtl[w * 64 + st * 16 + lane];
                float alpha = 1.0f - __expf(-sg * dte);
                float r0 = 1.0f / (1.0f + __expf(-acc[0]));
                float r1 = 1.0f / (1.0f + __expf(-acc[1]));
                float r2 = 1.0f / (1.0f + __expf(-acc[2]));
                uint2 o;
                o.x = packbf(r0, r1);
                o.y = packbf(r2, alpha);
                rgba[blockIdx.x * 256 + w * 64 + st * 16 + lane] = o;
            }
        }
    }
}

__global__ void render_kernel(const uint2* __restrict__ rgba,
                              const float* __restrict__ t_starts,
                              const float* __restrict__ t_ends,
                              const int* __restrict__ start,
                              const int* __restrict__ end,
                              float* __restrict__ out)
{
    int r = blockIdx.x * blockDim.x + threadIdx.x;
    if (r >= NR) return;
    int sb = start[r], e = end[r];
    float T = 1.0f, c0 = 0.0f, c1 = 0.0f, c2 = 0.0f, op = 0.0f, dp = 0.0f;
    for (int i = sb; i < e; ++i) {
        uint2 q = rgba[i];
        float vr = bflo(q.x & 0xffffu), vg = bflo(q.x >> 16);
        float vb = bflo(q.y & 0xffffu), va = bflo(q.y >> 16);
        float wgt = T * va;
        float tmid = 0.5f * (t_starts[i] + t_ends[i]);
        c0 += wgt * vr; c1 += wgt * vg; c2 += wgt * vb;
        op += wgt; dp += wgt * tmid;
        T *= (1.0f - va);
    }
    float bg = 1.0f - op;
    c0 += bg; c1 += bg; c2 += bg;
    out[3 * r + 0] = c0;
    out[3 * r + 1] = c1;
    out[3 * r + 2] = c2;
    out[3 * NR + r] = op;
    out[4 * NR + r] = dp;
}

extern "C" void kernel_launch(void* const* d_in, const int* in_sizes, int n_in,
                              void* d_out, int out_size, void* d_ws, size_t ws_size,
                              hipStream_t stream) {
    const float* rays_o   = (const float*)d_in[0];
    const float* viewdirs = (const float*)d_in[1];
    const float* t_starts = (const float*)d_in[2];
    const float* t_ends   = (const float*)d_in[3];
    const float* W1  = (const float*)d_in[4];
    const float* b1  = (const float*)d_in[5];
    const float* W2  = (const float*)d_in[6];
    const float* b2  = (const float*)d_in[7];
    const float* Wd  = (const float*)d_in[8];
    const float* bd  = (const float*)d_in[9];
    const float* Wf  = (const float*)d_in[10];
    const float* bf_ = (const float*)d_in[11];
    const float* Wr1 = (const float*)d_in[12];
    const float* br1 = (const float*)d_in[13];
    const float* Wr2 = (const float*)d_in[14];
    const float* br2 = (const float*)d_in[15];
    const int* ridx  = (const int*)d_in[16];
    float* out = (float*)d_out;

    char* ws = (char*)d_ws;
    uint2* rgba = (uint2*)ws;
    int* start = (int*)(ws + (size_t)NS * 8);
    int* end   = start + NR;
    uint4* wfrag = (uint4*)(ws + (size_t)NS * 8 + (size_t)NR * 8);

    build_frags<<<10, 256, 0, stream>>>(W1, W2, Wf, Wr1, Wd, Wr2, wfrag);
    init_bounds<<<NR / 256, 256, 0, stream>>>(start, end);
    find_bounds<<<NS / 256, 256, 0, stream>>>(ridx, start, end);
    fused_mlp<<<NS / 256, 256, 0, stream>>>(
        rays_o, viewdirs, t_starts, t_ends,
        b1, b2, bd, bf_, br1, br2, ridx, wfrag, rgba);
    render_kernel<<<NR / 256, 256, 0, stream>>>(rgba, t_starts, t_ends, start, end, out);
}